// Round 4
// baseline (2603.203 us; speedup 1.0000x reference)
//
#include <hip/hip_runtime.h>
#include <hip/hip_bf16.h>
#include <stdint.h>
#include <math.h>

#define DEV __device__ __forceinline__

typedef __hip_bfloat16 bf16;
typedef __attribute__((ext_vector_type(8))) __bf16 bf16x8;
typedef __attribute__((ext_vector_type(4))) float f32x4;
typedef __attribute__((ext_vector_type(2))) float f32x2;

static constexpr int B_ = 2;
static constexpr int T_ = 4096;
static constexpr int C_ = 2048;
static constexpr int H_ = 32;

// ---------- helpers ----------
DEV void gld_lds16(const void* g, void* l) {
  __builtin_amdgcn_global_load_lds((const __attribute__((address_space(1))) void*)g,
                                   (__attribute__((address_space(3))) void*)l, 16, 0, 0);
}
DEV float bfbits2f(unsigned short u) {
  unsigned int x = ((unsigned int)u) << 16;
  return __builtin_bit_cast(float, x);
}
DEV unsigned short f2bfbits(float f) { bf16 h = __float2bfloat16(f); return __builtin_bit_cast(unsigned short, h); }
DEV void store_bf16x4(bf16* p, f32x4 v) {
  ushort4 u;
  u.x = f2bfbits(v.x); u.y = f2bfbits(v.y); u.z = f2bfbits(v.z); u.w = f2bfbits(v.w);
  *reinterpret_cast<ushort4*>(p) = u;
}
DEV float wsum64(float v) {
#pragma unroll
  for (int m = 32; m > 0; m >>= 1) v += __shfl_xor(v, m, 64);
  return v;
}
template<int CTRL>
DEV float dpp_add(float v) {
  int x = __builtin_bit_cast(int, v);
  int y = __builtin_amdgcn_update_dpp(0, x, CTRL, 0xf, 0xf, false);
  return v + __builtin_bit_cast(float, y);
}
// sum across a 16-lane DPP row (lane bits 0..3 vary)
DEV float red16(float v) {
  v = dpp_add<0xB1>(v);    // quad_perm xor1
  v = dpp_add<0x4E>(v);    // quad_perm xor2
  v = dpp_add<0x124>(v);   // row_ror:4 (quads uniform -> adds neighbor quad)
  v = dpp_add<0x128>(v);   // row_ror:8
  return v;
}
// 2 packed bf16 dwords -> 4 f32 (1 instr/elem: lshl / and)
DEV f32x4 cvt4(uint2 u) {
  f32x4 o;
  o.x = __builtin_bit_cast(float, u.x << 16);
  o.y = __builtin_bit_cast(float, u.x & 0xFFFF0000u);
  o.z = __builtin_bit_cast(float, u.y << 16);
  o.w = __builtin_bit_cast(float, u.y & 0xFFFF0000u);
  return o;
}

// ---------- GEMM: C[m][n] = sum_k A[m][k]*B[n][k], bf16 in, f32 accum ----------
// 128x128 tile, BK=64, 4 waves (2x2), 16x16x32 MFMA, global_load_lds width-16.
// MODE: 0 f32 [M][N]; 2 bf16 flat; 3 bf16 tanh; 4 bf16 sigmoid;
//       7 bf16 transposed [B,H,T,64]; 8 f32 transposed wdec(ep+val);
//       9 bf16 transposed sigmoid(ep+val)
template<int MODE>
__global__ __launch_bounds__(256)
void gemm_bt(const bf16* __restrict__ A, const bf16* __restrict__ Bm,
             void* __restrict__ Cout, const float* __restrict__ ep,
             int N, int K, int T4)
{
  __shared__ bf16 lA[128 * 64];
  __shared__ bf16 lB[128 * 64];
  const int tid  = threadIdx.x;
  const int wave = tid >> 6;
  const int lane = tid & 63;
  const long brow = (long)blockIdx.x * 128;
  const long bcol = (long)blockIdx.y * 128;
  const int wr = wave >> 1, wc = wave & 1;

  f32x4 acc[4][4];
#pragma unroll
  for (int m = 0; m < 4; ++m)
#pragma unroll
    for (int n = 0; n < 4; ++n)
      acc[m][n] = f32x4{0.f, 0.f, 0.f, 0.f};

  const bf16* pa = A  + (size_t)(brow + wave * 32 + (lane >> 3)) * K + (lane & 7) * 8;
  const bf16* pb = Bm + (size_t)(bcol + wave * 32 + (lane >> 3)) * K + (lane & 7) * 8;

  for (int k0 = 0; k0 < K; k0 += 64) {
#pragma unroll
    for (int i = 0; i < 4; ++i) gld_lds16(pa + (size_t)i * 8 * K, &lA[(wave * 4 + i) * 512]);
#pragma unroll
    for (int i = 0; i < 4; ++i) gld_lds16(pb + (size_t)i * 8 * K, &lB[(wave * 4 + i) * 512]);
    pa += 64; pb += 64;
    __syncthreads();
#pragma unroll
    for (int kk = 0; kk < 2; ++kk) {
      bf16x8 af[4], bfv[4];
#pragma unroll
      for (int m = 0; m < 4; ++m)
        af[m] = *(const bf16x8*)&lA[(wr * 64 + m * 16 + (lane & 15)) * 64 + kk * 32 + (lane >> 4) * 8];
#pragma unroll
      for (int n = 0; n < 4; ++n)
        bfv[n] = *(const bf16x8*)&lB[(wc * 64 + n * 16 + (lane & 15)) * 64 + kk * 32 + (lane >> 4) * 8];
#pragma unroll
      for (int m = 0; m < 4; ++m)
#pragma unroll
        for (int n = 0; n < 4; ++n)
          acc[m][n] = __builtin_amdgcn_mfma_f32_16x16x32_bf16(af[m], bfv[n], acc[m][n], 0, 0, 0);
    }
    __syncthreads();
  }

  const int cr = (lane >> 4) * 4;
  const int cc = lane & 15;
#pragma unroll
  for (int m = 0; m < 4; ++m) {
#pragma unroll
    for (int n = 0; n < 4; ++n) {
#pragma unroll
      for (int j = 0; j < 4; ++j) {
        long gm = brow + wr * 64 + m * 16 + cr + j;
        long gn = bcol + wc * 64 + n * 16 + cc;
        float val = acc[m][n][j];
        if constexpr (MODE == 0) {
          ((float*)Cout)[gm * N + gn] = val;
        } else if constexpr (MODE == 2) {
          ((bf16*)Cout)[gm * N + gn] = __float2bfloat16(val);
        } else if constexpr (MODE == 3) {
          ((bf16*)Cout)[gm * N + gn] = __float2bfloat16(tanhf(val));
        } else if constexpr (MODE == 4) {
          ((bf16*)Cout)[gm * N + gn] = __float2bfloat16(1.f / (1.f + expf(-val)));
        } else if constexpr (MODE == 7) {
          long b = gm / T4, t = gm % T4;
          ((bf16*)Cout)[((b * (N >> 6) + (gn >> 6)) * T4 + t) * 64 + (gn & 63)] = __float2bfloat16(val);
        } else if constexpr (MODE == 8) {
          float u = ep[gn] + val;                 // w0 + lora
          float w = -log1pf(expf(-u)) - 0.5f;     // -softplus(-u) - 0.5
          float wd = expf(-expf(w));
          long b = gm / T4, t = gm % T4;
          ((float*)Cout)[((b * (N >> 6) + (gn >> 6)) * T4 + t) * 64 + (gn & 63)] = wd;
        } else if constexpr (MODE == 9) {
          float sg = 1.f / (1.f + expf(-(ep[gn] + val)));
          long b = gm / T4, t = gm % T4;
          ((bf16*)Cout)[((b * (N >> 6) + (gn >> 6)) * T4 + t) * 64 + (gn & 63)] = __float2bfloat16(sg);
        }
      }
    }
  }
}

// ---------- single token-shift mix ----------
__global__ __launch_bounds__(256)
void mix1(const float* __restrict__ x, const float* __restrict__ coef,
          bf16* __restrict__ out)
{
  size_t e = ((size_t)blockIdx.x * 256 + threadIdx.x) * 4;
  int c = (int)(e & (C_ - 1));
  size_t m = e >> 11;
  f32x4 xc = *(const f32x4*)(x + e);
  f32x4 xp;
  if ((m & (T_ - 1)) == 0) xp = f32x4{0.f, 0.f, 0.f, 0.f};
  else                     xp = *(const f32x4*)(x + e - C_);
  f32x4 cf = *(const f32x4*)(coef + c);
  store_bf16x4(out + e, xc + (xp - xc) * cf);
}

// ---------- f32 -> bf16 weight convert (4M elems) ----------
__global__ __launch_bounds__(256)
void cvt1(const float* __restrict__ s, bf16* __restrict__ d)
{
  size_t e = ((size_t)blockIdx.x * 256 + threadIdx.x) * 4;
  store_bf16x4(d + e, *(const f32x4*)(s + e));
}

// ---------- transpose+pad LoRA weights to [NP][RP] bf16, dst[n][r]=src[r][n] ----------
struct TPJob { const float* s; bf16* d; int R, Cs, NP, RP; };
struct TP8 { TPJob j[8]; };
__global__ __launch_bounds__(256)
void tpad(TP8 jobs)
{
  TPJob J = jobs.j[blockIdx.y];
  int i = blockIdx.x * 256 + threadIdx.x;
  int tot = J.NP * J.RP;
  if (i >= tot) return;
  int n = i / J.RP, r = i - n * J.RP;
  float v = (n < J.Cs && r < J.R) ? J.s[(size_t)r * J.Cs + n] : 0.f;
  J.d[i] = __float2bfloat16(v);
}

// ---------- prescan: kk-norm, k-adjust, v-mix, bonus scalar; in-place b/kkn ----------
__global__ __launch_bounds__(256)
void prescan2(const bf16* __restrict__ r16, bf16* __restrict__ k16,
              bf16* __restrict__ v16, bf16* __restrict__ ab,      // a_sig_t -> b16
              bf16* __restrict__ vn16,                            // v_sig_t -> kkn16
              const float* __restrict__ vfirst, const float* __restrict__ kkc,
              const float* __restrict__ kac, const float* __restrict__ rk,
              float* __restrict__ sbonus)
{
  const int wid = threadIdx.x >> 6;
  const int lane = threadIdx.x & 63;
  const long id = (long)blockIdx.x * 4 + wid;   // bh*T + t
  const long bh = id >> 12;
  const long t = id & (T_ - 1);
  const long b = bh >> 5, h = bh & (H_ - 1);
  const long mrow = b * T_ + t;
  const int c = (int)(h * 64 + lane);
  const size_t tp = (size_t)id * 64 + lane;
  float k  = __bfloat162float(k16[tp]);
  float v  = __bfloat162float(v16[tp]);
  float r  = __bfloat162float(r16[tp]);
  float a  = __bfloat162float(ab[tp]);
  float vs = __bfloat162float(vn16[tp]);
  float vf = vfirst[mrow * C_ + c];
  float kkv = k * kkc[c];
  float ssum = wsum64(kkv * kkv);
  float kkn = kkv / fmaxf(sqrtf(ssum), 1e-12f);
  float kn = k * (1.f + (a - 1.f) * kac[c]);
  float vn = v + (vf - v) * vs;
  k16[tp] = __float2bfloat16(kn);
  v16[tp] = __float2bfloat16(vn);
  ab[tp]  = __float2bfloat16(kkn * a);   // b = kk * a
  vn16[tp] = __float2bfloat16(kkn);      // scan negates for a_t = -kk
  float bs = wsum64(r * kn * rk[c]);     // bonus scalar per (b,h,t)
  if (lane == 0) sbonus[id] = bs;
}

// ---------- WKV7 sequential scan, v4 ----------
// 128 blocks x 512 threads: block = (head bh, half); wave wv owns v-rows
// (half*8+wv)*4 .. +4. Lane = vl*16+kq: row (group*4+vl), k-cols [kq*4, kq*4+4).
// Direct global->VGPR double-buffered loads (unroll-2, static indexing);
// packed-f32 math; 16-lane DPP reductions; w stream f32 for precision.
struct SS {
  uint2 r0, r1, k0, k1, n0, n1, b0, b1;
  f32x4 w0, w1;
  unsigned short v0, v1;
};
DEV SS ldss(const uint2* pr, const uint2* pk, const uint2* pn, const uint2* pb,
            const f32x4* pw, const unsigned short* pv, int ss, int kq, int row)
{
  SS s;
  int i0 = ss * 32 + kq, i1 = i0 + 16;     // uint2/f32x4 units, 16 per step
  s.r0 = pr[i0]; s.r1 = pr[i1];
  s.k0 = pk[i0]; s.k1 = pk[i1];
  s.n0 = pn[i0]; s.n1 = pn[i1];
  s.b0 = pb[i0]; s.b1 = pb[i1];
  s.w0 = pw[i0]; s.w1 = pw[i1];
  int j0 = ss * 128 + row, j1 = j0 + 64;
  s.v0 = pv[j0]; s.v1 = pv[j1];
  return s;
}
DEV float dostep(f32x4& S, uint2 ru, uint2 ku, uint2 nu, uint2 bu,
                 f32x4 W, unsigned short vus)
{
  f32x4 R = cvt4(ru), K = cvt4(ku), N = cvt4(nu), Bv = cvt4(bu);
  float vt = bfbits2f(vus);
  f32x2 acc = S.xy * N.xy;
  acc = __builtin_elementwise_fma(S.zw, N.zw, acc);
  float sa = red16(acc.x + acc.y);
  float nsa = -sa;                               // a_t = -kk
  f32x2 ns2 = f32x2{nsa, nsa}, vt2 = f32x2{vt, vt};
  S.xy = __builtin_elementwise_fma(vt2, K.xy,
           __builtin_elementwise_fma(ns2, Bv.xy, S.xy * W.xy));
  S.zw = __builtin_elementwise_fma(vt2, K.zw,
           __builtin_elementwise_fma(ns2, Bv.zw, S.zw * W.zw));
  f32x2 yq = S.xy * R.xy;
  yq = __builtin_elementwise_fma(S.zw, R.zw, yq);
  return red16(yq.x + yq.y);
}
__global__ __launch_bounds__(512, 2)
void wkv_scan4(const bf16* __restrict__ r16, const float* __restrict__ w32,
               const bf16* __restrict__ k16, const bf16* __restrict__ v16,
               const bf16* __restrict__ n16, const bf16* __restrict__ b16,
               bf16* __restrict__ y16)
{
  const int bh = blockIdx.x >> 1;
  const int half = blockIdx.x & 1;
  const int wv = threadIdx.x >> 6;
  const int lane = threadIdx.x & 63;
  const int vl = lane >> 4;
  const int kq = lane & 15;
  const int row = (half * 8 + wv) * 4 + vl;     // 0..63
  const size_t eb = (size_t)bh * (T_ * 64);
  const uint2* pr = (const uint2*)(r16 + eb);
  const uint2* pk = (const uint2*)(k16 + eb);
  const uint2* pn = (const uint2*)(n16 + eb);
  const uint2* pb = (const uint2*)(b16 + eb);
  const f32x4* pw = (const f32x4*)(w32 + eb);
  const unsigned short* pv = (const unsigned short*)(v16 + eb);
  bf16* py = y16 + eb + row;

  f32x4 S = f32x4{0.f, 0.f, 0.f, 0.f};
  const int NS = T_ / 2;                        // supersteps (2 t-steps each)

  SS bA = ldss(pr, pk, pn, pb, pw, pv, 0, kq, row);
  SS bB = ldss(pr, pk, pn, pb, pw, pv, 1, kq, row);

  for (int ss = 0; ss < NS; ss += 2) {
    int nA = ss + 2 < NS ? ss + 2 : NS - 1;
    int nB = ss + 3 < NS ? ss + 3 : NS - 1;
    SS pA = ldss(pr, pk, pn, pb, pw, pv, nA, kq, row);
    {
      int t = 2 * ss;
      float y0 = dostep(S, bA.r0, bA.k0, bA.n0, bA.b0, bA.w0, bA.v0);
      if (kq == 0) py[(size_t)t * 64] = __float2bfloat16(y0);
      float y1 = dostep(S, bA.r1, bA.k1, bA.n1, bA.b1, bA.w1, bA.v1);
      if (kq == 0) py[(size_t)(t + 1) * 64] = __float2bfloat16(y1);
    }
    SS pB = ldss(pr, pk, pn, pb, pw, pv, nB, kq, row);
    {
      int t = 2 * ss + 2;
      float y0 = dostep(S, bB.r0, bB.k0, bB.n0, bB.b0, bB.w0, bB.v0);
      if (kq == 0) py[(size_t)t * 64] = __float2bfloat16(y0);
      float y1 = dostep(S, bB.r1, bB.k1, bB.n1, bB.b1, bB.w1, bB.v1);
      if (kq == 0) py[(size_t)(t + 1) * 64] = __float2bfloat16(y1);
    }
    bA = pA; bB = pB;
  }
}

// ---------- post: GroupNorm + bonus + gate -> bf16 A for output GEMM ----------
__global__ __launch_bounds__(256)
void postk2(const bf16* __restrict__ y16, const bf16* __restrict__ v16,
            const float* __restrict__ sbonus, const bf16* __restrict__ g16,
            const float* __restrict__ lnw, const float* __restrict__ lnb,
            bf16* __restrict__ opre)
{
  const int wid = threadIdx.x >> 6;
  const int lane = threadIdx.x & 63;
  const long id = (long)blockIdx.x * 4 + wid;
  const long bh = id >> 12;
  const long t = id & (T_ - 1);
  const long b = bh >> 5, h = bh & (H_ - 1);
  const long mrow = b * T_ + t;
  const int c = (int)(h * 64 + lane);
  const size_t tp = (size_t)id * 64 + lane;
  float y = __bfloat162float(y16[tp]);
  float mu = wsum64(y) * (1.f / 64.f);
  float d = y - mu;
  float var = wsum64(d * d) * (1.f / 64.f);
  float yn = d * rsqrtf(var + 0.00064f) * lnw[c] + lnb[c];
  float outv = (yn + sbonus[id] * __bfloat162float(v16[tp]))
               * __bfloat162float(g16[mrow * C_ + c]);
  opre[mrow * C_ + c] = __float2bfloat16(outv);
}

// ---------- launch ----------
extern "C" void kernel_launch(void* const* d_in, const int* in_sizes, int n_in,
                              void* d_out, int out_size, void* d_ws, size_t ws_size,
                              hipStream_t stream)
{
  const float* x    = (const float*)d_in[0];
  const float* vfst = (const float*)d_in[1];
  const float* x_r  = (const float*)d_in[2];
  const float* x_w  = (const float*)d_in[3];
  const float* x_k  = (const float*)d_in[4];
  const float* x_v  = (const float*)d_in[5];
  const float* x_a  = (const float*)d_in[6];
  const float* x_g  = (const float*)d_in[7];
  const float* w0   = (const float*)d_in[8];
  const float* w1   = (const float*)d_in[9];
  const float* w2   = (const float*)d_in[10];
  const float* a0   = (const float*)d_in[11];
  const float* a1   = (const float*)d_in[12];
  const float* a2   = (const float*)d_in[13];
  const float* v0   = (const float*)d_in[14];
  const float* v1   = (const float*)d_in[15];
  const float* v2   = (const float*)d_in[16];
  const float* g1   = (const float*)d_in[17];
  const float* g2   = (const float*)d_in[18];
  const float* k_k  = (const float*)d_in[19];
  const float* k_a  = (const float*)d_in[20];
  const float* r_k  = (const float*)d_in[21];
  const float* W_r  = (const float*)d_in[22];
  const float* W_k  = (const float*)d_in[23];
  const float* W_v  = (const float*)d_in[24];
  const float* W_o  = (const float*)d_in[25];
  const float* lnw  = (const float*)d_in[26];
  const float* lnb  = (const float*)d_in[27];

  const size_t MB = 1048576ULL;
  const size_t HK = 524288ULL;
  if (ws_size < 248 * MB) return;   // proven-safe budget (round 3 passed)

  char* ws = (char*)d_ws;
  bf16* r16  = (bf16*)(ws + 0 * MB);     // [B,H,T,64] bf16
  bf16* k16  = (bf16*)(ws + 32 * MB);
  bf16* v16  = (bf16*)(ws + 64 * MB);
  float* w32 = (float*)(ws + 96 * MB);   // [B,H,T,64] f32 decay (96..160)
  bf16* opre = (bf16*)(ws + 96 * MB);    // postk output; w32 dead after scan
  bf16* asig = (bf16*)(ws + 160 * MB);   // a_sig_t -> b16 in-place at prescan
  bf16* vsig = (bf16*)(ws + 192 * MB);   // v_sig_t -> kkn16 in-place
  bf16* w1t = (bf16*)(ws + 224 * MB);
  bf16* a1t = (bf16*)(ws + 224 * MB + HK);
  bf16* v1t = (bf16*)(ws + 225 * MB);
  bf16* g1t = (bf16*)(ws + 225 * MB + HK); // 1MB
  bf16* w2t = (bf16*)(ws + 226 * MB + HK);
  bf16* a2t = (bf16*)(ws + 227 * MB);
  bf16* v2t = (bf16*)(ws + 227 * MB + HK);
  bf16* g2t = (bf16*)(ws + 228 * MB);      // 1MB -> ends 229MB
  bf16* h_w = (bf16*)(ws + 229 * MB);      // [8192][128] 2MB
  bf16* h_a = (bf16*)(ws + 231 * MB);
  bf16* h_v = (bf16*)(ws + 233 * MB);
  bf16* h_g = (bf16*)(ws + 235 * MB);      // [8192][256] 4MB
  float* sb = (float*)(ws + 239 * MB);     // bonus scalars [B,H,T] 1MB
  bf16* WB  = (bf16*)(ws + 240 * MB);      // 8MB sequential weight-cvt buffer
  bf16* g16 = (bf16*)d_out;                // gate bf16, d_out lower half
  bf16* MIX = (bf16*)((char*)d_out + 32 * MB); // recycled mix buffer (dead pre-scan)
  bf16* y16 = (bf16*)((char*)d_out + 32 * MB); // scan out over dead MIX region

  TP8 jobs;
  jobs.j[0] = TPJob{ w1, w1t, 2048,   96,  128, 2048 };
  jobs.j[1] = TPJob{ a1, a1t, 2048,   96,  128, 2048 };
  jobs.j[2] = TPJob{ v1, v1t, 2048,   64,  128, 2048 };
  jobs.j[3] = TPJob{ g1, g1t, 2048,  256,  256, 2048 };
  jobs.j[4] = TPJob{ w2, w2t,   96, 2048, 2048,  128 };
  jobs.j[5] = TPJob{ a2, a2t,   96, 2048, 2048,  128 };
  jobs.j[6] = TPJob{ v2, v2t,   64, 2048, 2048,  128 };
  jobs.j[7] = TPJob{ g2, g2t,  256, 2048, 2048,  256 };
  tpad<<<dim3(2048, 8), 256, 0, stream>>>(jobs);

  // LoRA stage-1 (mix recomputed per GEMM; activation fused)
  mix1<<<dim3(16384), 256, 0, stream>>>(x, x_w, MIX);
  gemm_bt<3><<<dim3(64, 1), 256, 0, stream>>>(MIX, w1t, h_w, nullptr, 128, 2048, 0);
  mix1<<<dim3(16384), 256, 0, stream>>>(x, x_a, MIX);
  gemm_bt<2><<<dim3(64, 1), 256, 0, stream>>>(MIX, a1t, h_a, nullptr, 128, 2048, 0);
  mix1<<<dim3(16384), 256, 0, stream>>>(x, x_v, MIX);
  gemm_bt<2><<<dim3(64, 1), 256, 0, stream>>>(MIX, v1t, h_v, nullptr, 128, 2048, 0);
  mix1<<<dim3(16384), 256, 0, stream>>>(x, x_g, MIX);
  gemm_bt<4><<<dim3(64, 2), 256, 0, stream>>>(MIX, g1t, h_g, nullptr, 256, 2048, 0);

  // LoRA stage-2 (wdec f32 / sigmoids fused, head-transposed; gate -> d_out)
  gemm_bt<8><<<dim3(64, 16), 256, 0, stream>>>(h_w, w2t, w32, w0, 2048, 128, T_);
  gemm_bt<9><<<dim3(64, 16), 256, 0, stream>>>(h_a, a2t, asig, a0, 2048, 128, T_);
  gemm_bt<9><<<dim3(64, 16), 256, 0, stream>>>(h_v, v2t, vsig, v0, 2048, 128, T_);
  gemm_bt<2><<<dim3(64, 16), 256, 0, stream>>>(h_g, g2t, g16, nullptr, 2048, 256, 0);

  // big projections (weight cvt + mix recycled buffers) -> bf16 [B,H,T,64]
  cvt1<<<dim3(4096), 256, 0, stream>>>(W_r, WB);
  mix1<<<dim3(16384), 256, 0, stream>>>(x, x_r, MIX);
  gemm_bt<7><<<dim3(64, 16), 256, 0, stream>>>(MIX, WB, r16, nullptr, 2048, 2048, T_);
  cvt1<<<dim3(4096), 256, 0, stream>>>(W_k, WB);
  mix1<<<dim3(16384), 256, 0, stream>>>(x, x_k, MIX);
  gemm_bt<7><<<dim3(64, 16), 256, 0, stream>>>(MIX, WB, k16, nullptr, 2048, 2048, T_);
  cvt1<<<dim3(4096), 256, 0, stream>>>(W_v, WB);
  mix1<<<dim3(16384), 256, 0, stream>>>(x, x_v, MIX);
  gemm_bt<7><<<dim3(64, 16), 256, 0, stream>>>(MIX, WB, v16, nullptr, 2048, 2048, T_);

  prescan2<<<dim3(65536), 256, 0, stream>>>(r16, k16, v16, asig, vsig,
                                            vfst, k_k, k_a, r_k, sb);
  wkv_scan4<<<dim3(128), 512, 0, stream>>>(r16, w32, k16, v16, vsig, asig, y16);
  postk2<<<dim3(65536), 256, 0, stream>>>(y16, v16, sb, g16, lnw, lnb, opre);

  cvt1<<<dim3(4096), 256, 0, stream>>>(W_o, WB);
  gemm_bt<0><<<dim3(64, 16), 256, 0, stream>>>(opre, WB, (float*)d_out, nullptr, 2048, 2048, 0);
}

// Round 5
// 1951.912 us; speedup vs baseline: 1.3337x; 1.3337x over previous
//
#include <hip/hip_runtime.h>
#include <hip/hip_bf16.h>
#include <stdint.h>
#include <math.h>

#define DEV __device__ __forceinline__

typedef __hip_bfloat16 bf16;
typedef __attribute__((ext_vector_type(8))) __bf16 bf16x8;
typedef __attribute__((ext_vector_type(4))) float f32x4;
typedef __attribute__((ext_vector_type(2))) float f32x2;

static constexpr int B_ = 2;
static constexpr int T_ = 4096;
static constexpr int C_ = 2048;
static constexpr int H_ = 32;

// ---------- helpers ----------
DEV void gld_lds16(const void* g, void* l) {
  __builtin_amdgcn_global_load_lds((const __attribute__((address_space(1))) void*)g,
                                   (__attribute__((address_space(3))) void*)l, 16, 0, 0);
}
DEV float bfbits2f(unsigned short u) {
  unsigned int x = ((unsigned int)u) << 16;
  return __builtin_bit_cast(float, x);
}
DEV unsigned short f2bfbits(float f) { bf16 h = __float2bfloat16(f); return __builtin_bit_cast(unsigned short, h); }
DEV void store_bf16x4(bf16* p, f32x4 v) {
  ushort4 u;
  u.x = f2bfbits(v.x); u.y = f2bfbits(v.y); u.z = f2bfbits(v.z); u.w = f2bfbits(v.w);
  *reinterpret_cast<ushort4*>(p) = u;
}
DEV float wsum64(float v) {
#pragma unroll
  for (int m = 32; m > 0; m >>= 1) v += __shfl_xor(v, m, 64);
  return v;
}
template<int CTRL>
DEV float dpp_add(float v) {
  int x = __builtin_bit_cast(int, v);
  int y = __builtin_amdgcn_update_dpp(0, x, CTRL, 0xf, 0xf, false);
  return v + __builtin_bit_cast(float, y);
}
// sum across a 16-lane DPP row (lane bits 0..3 vary)
DEV float red16(float v) {
  v = dpp_add<0xB1>(v);    // quad_perm xor1
  v = dpp_add<0x4E>(v);    // quad_perm xor2
  v = dpp_add<0x124>(v);   // row_ror:4
  v = dpp_add<0x128>(v);   // row_ror:8
  return v;
}
// 2 packed bf16 dwords -> 4 f32 (1 instr/elem)
DEV f32x4 cvt4(uint2 u) {
  f32x4 o;
  o.x = __builtin_bit_cast(float, u.x << 16);
  o.y = __builtin_bit_cast(float, u.x & 0xFFFF0000u);
  o.z = __builtin_bit_cast(float, u.y << 16);
  o.w = __builtin_bit_cast(float, u.y & 0xFFFF0000u);
  return o;
}

// ---------- GEMM: C[m][n] = sum_k A[m][k]*B[n][k], bf16 in, f32 accum ----------
// 128x128 tile, BK=64, 4 waves (2x2), 16x16x32 MFMA, global_load_lds width-16.
// MODE: 0 f32 [M][N]; 2 bf16 flat; 3 bf16 tanh; 4 bf16 sigmoid;
//       7 bf16 transposed [B,H,T,64]; 8 f32 transposed wdec(ep+val);
//       9 bf16 transposed sigmoid(ep+val)
template<int MODE>
__global__ __launch_bounds__(256)
void gemm_bt(const bf16* __restrict__ A, const bf16* __restrict__ Bm,
             void* __restrict__ Cout, const float* __restrict__ ep,
             int N, int K, int T4)
{
  __shared__ bf16 lA[128 * 64];
  __shared__ bf16 lB[128 * 64];
  const int tid  = threadIdx.x;
  const int wave = tid >> 6;
  const int lane = tid & 63;
  const long brow = (long)blockIdx.x * 128;
  const long bcol = (long)blockIdx.y * 128;
  const int wr = wave >> 1, wc = wave & 1;

  f32x4 acc[4][4];
#pragma unroll
  for (int m = 0; m < 4; ++m)
#pragma unroll
    for (int n = 0; n < 4; ++n)
      acc[m][n] = f32x4{0.f, 0.f, 0.f, 0.f};

  const bf16* pa = A  + (size_t)(brow + wave * 32 + (lane >> 3)) * K + (lane & 7) * 8;
  const bf16* pb = Bm + (size_t)(bcol + wave * 32 + (lane >> 3)) * K + (lane & 7) * 8;

  for (int k0 = 0; k0 < K; k0 += 64) {
#pragma unroll
    for (int i = 0; i < 4; ++i) gld_lds16(pa + (size_t)i * 8 * K, &lA[(wave * 4 + i) * 512]);
#pragma unroll
    for (int i = 0; i < 4; ++i) gld_lds16(pb + (size_t)i * 8 * K, &lB[(wave * 4 + i) * 512]);
    pa += 64; pb += 64;
    __syncthreads();
#pragma unroll
    for (int kk = 0; kk < 2; ++kk) {
      bf16x8 af[4], bfv[4];
#pragma unroll
      for (int m = 0; m < 4; ++m)
        af[m] = *(const bf16x8*)&lA[(wr * 64 + m * 16 + (lane & 15)) * 64 + kk * 32 + (lane >> 4) * 8];
#pragma unroll
      for (int n = 0; n < 4; ++n)
        bfv[n] = *(const bf16x8*)&lB[(wc * 64 + n * 16 + (lane & 15)) * 64 + kk * 32 + (lane >> 4) * 8];
#pragma unroll
      for (int m = 0; m < 4; ++m)
#pragma unroll
        for (int n = 0; n < 4; ++n)
          acc[m][n] = __builtin_amdgcn_mfma_f32_16x16x32_bf16(af[m], bfv[n], acc[m][n], 0, 0, 0);
    }
    __syncthreads();
  }

  const int cr = (lane >> 4) * 4;
  const int cc = lane & 15;
#pragma unroll
  for (int m = 0; m < 4; ++m) {
#pragma unroll
    for (int n = 0; n < 4; ++n) {
#pragma unroll
      for (int j = 0; j < 4; ++j) {
        long gm = brow + wr * 64 + m * 16 + cr + j;
        long gn = bcol + wc * 64 + n * 16 + cc;
        float val = acc[m][n][j];
        if constexpr (MODE == 0) {
          ((float*)Cout)[gm * N + gn] = val;
        } else if constexpr (MODE == 2) {
          ((bf16*)Cout)[gm * N + gn] = __float2bfloat16(val);
        } else if constexpr (MODE == 3) {
          ((bf16*)Cout)[gm * N + gn] = __float2bfloat16(tanhf(val));
        } else if constexpr (MODE == 4) {
          ((bf16*)Cout)[gm * N + gn] = __float2bfloat16(1.f / (1.f + expf(-val)));
        } else if constexpr (MODE == 7) {
          long b = gm / T4, t = gm % T4;
          ((bf16*)Cout)[((b * (N >> 6) + (gn >> 6)) * T4 + t) * 64 + (gn & 63)] = __float2bfloat16(val);
        } else if constexpr (MODE == 8) {
          float u = ep[gn] + val;                 // w0 + lora
          float w = -log1pf(expf(-u)) - 0.5f;     // -softplus(-u) - 0.5
          float wd = expf(-expf(w));
          long b = gm / T4, t = gm % T4;
          ((float*)Cout)[((b * (N >> 6) + (gn >> 6)) * T4 + t) * 64 + (gn & 63)] = wd;
        } else if constexpr (MODE == 9) {
          float sg = 1.f / (1.f + expf(-(ep[gn] + val)));
          long b = gm / T4, t = gm % T4;
          ((bf16*)Cout)[((b * (N >> 6) + (gn >> 6)) * T4 + t) * 64 + (gn & 63)] = __float2bfloat16(sg);
        }
      }
    }
  }
}

// ---------- single token-shift mix ----------
__global__ __launch_bounds__(256)
void mix1(const float* __restrict__ x, const float* __restrict__ coef,
          bf16* __restrict__ out)
{
  size_t e = ((size_t)blockIdx.x * 256 + threadIdx.x) * 4;
  int c = (int)(e & (C_ - 1));
  size_t m = e >> 11;
  f32x4 xc = *(const f32x4*)(x + e);
  f32x4 xp;
  if ((m & (T_ - 1)) == 0) xp = f32x4{0.f, 0.f, 0.f, 0.f};
  else                     xp = *(const f32x4*)(x + e - C_);
  f32x4 cf = *(const f32x4*)(coef + c);
  store_bf16x4(out + e, xc + (xp - xc) * cf);
}

// ---------- f32 -> bf16 weight convert (4M elems) ----------
__global__ __launch_bounds__(256)
void cvt1(const float* __restrict__ s, bf16* __restrict__ d)
{
  size_t e = ((size_t)blockIdx.x * 256 + threadIdx.x) * 4;
  store_bf16x4(d + e, *(const f32x4*)(s + e));
}

// ---------- transpose+pad LoRA weights to [NP][RP] bf16, dst[n][r]=src[r][n] ----------
struct TPJob { const float* s; bf16* d; int R, Cs, NP, RP; };
struct TP8 { TPJob j[8]; };
__global__ __launch_bounds__(256)
void tpad(TP8 jobs)
{
  TPJob J = jobs.j[blockIdx.y];
  int i = blockIdx.x * 256 + threadIdx.x;
  int tot = J.NP * J.RP;
  if (i >= tot) return;
  int n = i / J.RP, r = i - n * J.RP;
  float v = (n < J.Cs && r < J.R) ? J.s[(size_t)r * J.Cs + n] : 0.f;
  J.d[i] = __float2bfloat16(v);
}

// ---------- prescan: kk-norm, k-adjust, v-mix, bonus scalar; in-place b/kkn ----------
__global__ __launch_bounds__(256)
void prescan2(const bf16* __restrict__ r16, bf16* __restrict__ k16,
              bf16* __restrict__ v16, bf16* __restrict__ ab,      // a_sig_t -> b16
              bf16* __restrict__ vn16,                            // v_sig_t -> kkn16
              const float* __restrict__ vfirst, const float* __restrict__ kkc,
              const float* __restrict__ kac, const float* __restrict__ rk,
              float* __restrict__ sbonus)
{
  const int wid = threadIdx.x >> 6;
  const int lane = threadIdx.x & 63;
  const long id = (long)blockIdx.x * 4 + wid;   // bh*T + t
  const long bh = id >> 12;
  const long t = id & (T_ - 1);
  const long b = bh >> 5, h = bh & (H_ - 1);
  const long mrow = b * T_ + t;
  const int c = (int)(h * 64 + lane);
  const size_t tp = (size_t)id * 64 + lane;
  float k  = __bfloat162float(k16[tp]);
  float v  = __bfloat162float(v16[tp]);
  float r  = __bfloat162float(r16[tp]);
  float a  = __bfloat162float(ab[tp]);
  float vs = __bfloat162float(vn16[tp]);
  float vf = vfirst[mrow * C_ + c];
  float kkv = k * kkc[c];
  float ssum = wsum64(kkv * kkv);
  float kkn = kkv / fmaxf(sqrtf(ssum), 1e-12f);
  float kn = k * (1.f + (a - 1.f) * kac[c]);
  float vn = v + (vf - v) * vs;
  k16[tp] = __float2bfloat16(kn);
  v16[tp] = __float2bfloat16(vn);
  ab[tp]  = __float2bfloat16(kkn * a);   // b = kk * a
  vn16[tp] = __float2bfloat16(kkn);      // scan negates for a_t = -kk
  float bs = wsum64(r * kn * rk[c]);     // bonus scalar per (b,h,t)
  if (lane == 0) sbonus[id] = bs;
}

// ---------- WKV7 sequential scan, v5 ----------
// 256 blocks x 256 threads: block = (quarter, bh) with bid = quarter*64 + bh so
// all 4 quarters of a head land on ONE XCD (64 % 8 == 0) -> streams fetched once.
// Wave wv owns rows quarter*16 + wv*4 .. +4; lane = vl*16+kq -> row +vl, cols
// [kq*4, kq*4+4). Depth-4 register prefetch (8 t-steps in flight, static bufs);
// packed-f32 math; 16-lane DPP reductions; w stream f32.
struct SS {
  uint2 r0, r1, k0, k1, n0, n1, b0, b1;
  f32x4 w0, w1;
  unsigned short v0, v1;
};
DEV SS ldss(const uint2* pr, const uint2* pk, const uint2* pn, const uint2* pb,
            const f32x4* pw, const unsigned short* pv, int ss, int kq, int row)
{
  SS s;
  int i0 = ss * 32 + kq, i1 = i0 + 16;     // uint2/f32x4 units, 16 per step
  s.r0 = pr[i0]; s.r1 = pr[i1];
  s.k0 = pk[i0]; s.k1 = pk[i1];
  s.n0 = pn[i0]; s.n1 = pn[i1];
  s.b0 = pb[i0]; s.b1 = pb[i1];
  s.w0 = pw[i0]; s.w1 = pw[i1];
  int j0 = ss * 128 + row, j1 = j0 + 64;
  s.v0 = pv[j0]; s.v1 = pv[j1];
  return s;
}
DEV float dostep(f32x4& S, uint2 ru, uint2 ku, uint2 nu, uint2 bu,
                 f32x4 W, unsigned short vus)
{
  f32x4 R = cvt4(ru), K = cvt4(ku), N = cvt4(nu), Bv = cvt4(bu);
  float vt = bfbits2f(vus);
  f32x2 acc = S.xy * N.xy;
  acc = __builtin_elementwise_fma(S.zw, N.zw, acc);
  float sa = red16(acc.x + acc.y);
  float nsa = -sa;                               // a_t = -kk
  f32x2 ns2 = f32x2{nsa, nsa}, vt2 = f32x2{vt, vt};
  S.xy = __builtin_elementwise_fma(vt2, K.xy,
           __builtin_elementwise_fma(ns2, Bv.xy, S.xy * W.xy));
  S.zw = __builtin_elementwise_fma(vt2, K.zw,
           __builtin_elementwise_fma(ns2, Bv.zw, S.zw * W.zw));
  f32x2 yq = S.xy * R.xy;
  yq = __builtin_elementwise_fma(S.zw, R.zw, yq);
  return red16(yq.x + yq.y);
}
DEV void consume(f32x4& S, const SS& s, bf16* py, int t, int kq)
{
  float y0 = dostep(S, s.r0, s.k0, s.n0, s.b0, s.w0, s.v0);
  if (kq == 0) py[(size_t)t * 64] = __float2bfloat16(y0);
  float y1 = dostep(S, s.r1, s.k1, s.n1, s.b1, s.w1, s.v1);
  if (kq == 0) py[(size_t)(t + 1) * 64] = __float2bfloat16(y1);
}
__global__ __launch_bounds__(256, 1)
void wkv_scan5(const bf16* __restrict__ r16, const float* __restrict__ w32,
               const bf16* __restrict__ k16, const bf16* __restrict__ v16,
               const bf16* __restrict__ n16, const bf16* __restrict__ b16,
               bf16* __restrict__ y16)
{
  const int bh = blockIdx.x & 63;        // co-XCD: all quarters of a head share XCD
  const int quarter = blockIdx.x >> 6;
  const int wv = threadIdx.x >> 6;
  const int lane = threadIdx.x & 63;
  const int vl = lane >> 4;
  const int kq = lane & 15;
  const int row = quarter * 16 + wv * 4 + vl;   // 0..63
  const size_t eb = (size_t)bh * (T_ * 64);
  const uint2* pr = (const uint2*)(r16 + eb);
  const uint2* pk = (const uint2*)(k16 + eb);
  const uint2* pn = (const uint2*)(n16 + eb);
  const uint2* pb = (const uint2*)(b16 + eb);
  const f32x4* pw = (const f32x4*)(w32 + eb);
  const unsigned short* pv = (const unsigned short*)(v16 + eb);
  bf16* py = y16 + eb + row;

  f32x4 S = f32x4{0.f, 0.f, 0.f, 0.f};
  const int NS = T_ / 2;                        // 2048 supersteps, %4 == 0

  SS s0 = ldss(pr, pk, pn, pb, pw, pv, 0, kq, row);
  SS s1 = ldss(pr, pk, pn, pb, pw, pv, 1, kq, row);
  SS s2 = ldss(pr, pk, pn, pb, pw, pv, 2, kq, row);
  SS s3 = ldss(pr, pk, pn, pb, pw, pv, 3, kq, row);

  for (int ss = 0; ss < NS; ss += 4) {
    int n0 = ss + 4 < NS ? ss + 4 : NS - 1;
    int n1 = ss + 5 < NS ? ss + 5 : NS - 1;
    int n2 = ss + 6 < NS ? ss + 6 : NS - 1;
    int n3 = ss + 7 < NS ? ss + 7 : NS - 1;
    SS p0 = ldss(pr, pk, pn, pb, pw, pv, n0, kq, row);
    consume(S, s0, py, 2 * ss, kq);
    SS p1 = ldss(pr, pk, pn, pb, pw, pv, n1, kq, row);
    consume(S, s1, py, 2 * ss + 2, kq);
    SS p2 = ldss(pr, pk, pn, pb, pw, pv, n2, kq, row);
    consume(S, s2, py, 2 * ss + 4, kq);
    SS p3 = ldss(pr, pk, pn, pb, pw, pv, n3, kq, row);
    consume(S, s3, py, 2 * ss + 6, kq);
    s0 = p0; s1 = p1; s2 = p2; s3 = p3;
  }
}

// ---------- post: GroupNorm + bonus + gate -> bf16 A for output GEMM ----------
__global__ __launch_bounds__(256)
void postk2(const bf16* __restrict__ y16, const bf16* __restrict__ v16,
            const float* __restrict__ sbonus, const bf16* __restrict__ g16,
            const float* __restrict__ lnw, const float* __restrict__ lnb,
            bf16* __restrict__ opre)
{
  const int wid = threadIdx.x >> 6;
  const int lane = threadIdx.x & 63;
  const long id = (long)blockIdx.x * 4 + wid;
  const long bh = id >> 12;
  const long t = id & (T_ - 1);
  const long b = bh >> 5, h = bh & (H_ - 1);
  const long mrow = b * T_ + t;
  const int c = (int)(h * 64 + lane);
  const size_t tp = (size_t)id * 64 + lane;
  float y = __bfloat162float(y16[tp]);
  float mu = wsum64(y) * (1.f / 64.f);
  float d = y - mu;
  float var = wsum64(d * d) * (1.f / 64.f);
  float yn = d * rsqrtf(var + 0.00064f) * lnw[c] + lnb[c];
  float outv = (yn + sbonus[id] * __bfloat162float(v16[tp]))
               * __bfloat162float(g16[mrow * C_ + c]);
  opre[mrow * C_ + c] = __float2bfloat16(outv);
}

// ---------- launch ----------
extern "C" void kernel_launch(void* const* d_in, const int* in_sizes, int n_in,
                              void* d_out, int out_size, void* d_ws, size_t ws_size,
                              hipStream_t stream)
{
  const float* x    = (const float*)d_in[0];
  const float* vfst = (const float*)d_in[1];
  const float* x_r  = (const float*)d_in[2];
  const float* x_w  = (const float*)d_in[3];
  const float* x_k  = (const float*)d_in[4];
  const float* x_v  = (const float*)d_in[5];
  const float* x_a  = (const float*)d_in[6];
  const float* x_g  = (const float*)d_in[7];
  const float* w0   = (const float*)d_in[8];
  const float* w1   = (const float*)d_in[9];
  const float* w2   = (const float*)d_in[10];
  const float* a0   = (const float*)d_in[11];
  const float* a1   = (const float*)d_in[12];
  const float* a2   = (const float*)d_in[13];
  const float* v0   = (const float*)d_in[14];
  const float* v1   = (const float*)d_in[15];
  const float* v2   = (const float*)d_in[16];
  const float* g1   = (const float*)d_in[17];
  const float* g2   = (const float*)d_in[18];
  const float* k_k  = (const float*)d_in[19];
  const float* k_a  = (const float*)d_in[20];
  const float* r_k  = (const float*)d_in[21];
  const float* W_r  = (const float*)d_in[22];
  const float* W_k  = (const float*)d_in[23];
  const float* W_v  = (const float*)d_in[24];
  const float* W_o  = (const float*)d_in[25];
  const float* lnw  = (const float*)d_in[26];
  const float* lnb  = (const float*)d_in[27];

  const size_t MB = 1048576ULL;
  const size_t HK = 524288ULL;
  if (ws_size < 248 * MB) return;   // proven-safe budget (round 3 passed)

  char* ws = (char*)d_ws;
  bf16* r16  = (bf16*)(ws + 0 * MB);     // [B,H,T,64] bf16
  bf16* k16  = (bf16*)(ws + 32 * MB);
  bf16* v16  = (bf16*)(ws + 64 * MB);
  float* w32 = (float*)(ws + 96 * MB);   // [B,H,T,64] f32 decay (96..160)
  bf16* opre = (bf16*)(ws + 96 * MB);    // postk output; w32 dead after scan
  bf16* asig = (bf16*)(ws + 160 * MB);   // a_sig_t -> b16 in-place at prescan
  bf16* vsig = (bf16*)(ws + 192 * MB);   // v_sig_t -> kkn16 in-place
  bf16* w1t = (bf16*)(ws + 224 * MB);
  bf16* a1t = (bf16*)(ws + 224 * MB + HK);
  bf16* v1t = (bf16*)(ws + 225 * MB);
  bf16* g1t = (bf16*)(ws + 225 * MB + HK); // 1MB
  bf16* w2t = (bf16*)(ws + 226 * MB + HK);
  bf16* a2t = (bf16*)(ws + 227 * MB);
  bf16* v2t = (bf16*)(ws + 227 * MB + HK);
  bf16* g2t = (bf16*)(ws + 228 * MB);      // 1MB -> ends 229MB
  bf16* h_w = (bf16*)(ws + 229 * MB);      // [8192][128] 2MB
  bf16* h_a = (bf16*)(ws + 231 * MB);
  bf16* h_v = (bf16*)(ws + 233 * MB);
  bf16* h_g = (bf16*)(ws + 235 * MB);      // [8192][256] 4MB
  float* sb = (float*)(ws + 239 * MB);     // bonus scalars [B,H,T] 1MB
  bf16* WB  = (bf16*)(ws + 240 * MB);      // 8MB sequential weight-cvt buffer
  bf16* g16 = (bf16*)d_out;                // gate bf16, d_out lower half
  bf16* MIX = (bf16*)((char*)d_out + 32 * MB); // recycled mix buffer (dead pre-scan)
  bf16* y16 = (bf16*)((char*)d_out + 32 * MB); // scan out over dead MIX region

  TP8 jobs;
  jobs.j[0] = TPJob{ w1, w1t, 2048,   96,  128, 2048 };
  jobs.j[1] = TPJob{ a1, a1t, 2048,   96,  128, 2048 };
  jobs.j[2] = TPJob{ v1, v1t, 2048,   64,  128, 2048 };
  jobs.j[3] = TPJob{ g1, g1t, 2048,  256,  256, 2048 };
  jobs.j[4] = TPJob{ w2, w2t,   96, 2048, 2048,  128 };
  jobs.j[5] = TPJob{ a2, a2t,   96, 2048, 2048,  128 };
  jobs.j[6] = TPJob{ v2, v2t,   64, 2048, 2048,  128 };
  jobs.j[7] = TPJob{ g2, g2t,  256, 2048, 2048,  256 };
  tpad<<<dim3(2048, 8), 256, 0, stream>>>(jobs);

  // LoRA stage-1 (mix recomputed per GEMM; activation fused)
  mix1<<<dim3(16384), 256, 0, stream>>>(x, x_w, MIX);
  gemm_bt<3><<<dim3(64, 1), 256, 0, stream>>>(MIX, w1t, h_w, nullptr, 128, 2048, 0);
  mix1<<<dim3(16384), 256, 0, stream>>>(x, x_a, MIX);
  gemm_bt<2><<<dim3(64, 1), 256, 0, stream>>>(MIX, a1t, h_a, nullptr, 128, 2048, 0);
  mix1<<<dim3(16384), 256, 0, stream>>>(x, x_v, MIX);
  gemm_bt<2><<<dim3(64, 1), 256, 0, stream>>>(MIX, v1t, h_v, nullptr, 128, 2048, 0);
  mix1<<<dim3(16384), 256, 0, stream>>>(x, x_g, MIX);
  gemm_bt<4><<<dim3(64, 2), 256, 0, stream>>>(MIX, g1t, h_g, nullptr, 256, 2048, 0);

  // LoRA stage-2 (wdec f32 / sigmoids fused, head-transposed; gate -> d_out)
  gemm_bt<8><<<dim3(64, 16), 256, 0, stream>>>(h_w, w2t, w32, w0, 2048, 128, T_);
  gemm_bt<9><<<dim3(64, 16), 256, 0, stream>>>(h_a, a2t, asig, a0, 2048, 128, T_);
  gemm_bt<9><<<dim3(64, 16), 256, 0, stream>>>(h_v, v2t, vsig, v0, 2048, 128, T_);
  gemm_bt<2><<<dim3(64, 16), 256, 0, stream>>>(h_g, g2t, g16, nullptr, 2048, 256, 0);

  // big projections (weight cvt + mix recycled buffers) -> bf16 [B,H,T,64]
  cvt1<<<dim3(4096), 256, 0, stream>>>(W_r, WB);
  mix1<<<dim3(16384), 256, 0, stream>>>(x, x_r, MIX);
  gemm_bt<7><<<dim3(64, 16), 256, 0, stream>>>(MIX, WB, r16, nullptr, 2048, 2048, T_);
  cvt1<<<dim3(4096), 256, 0, stream>>>(W_k, WB);
  mix1<<<dim3(16384), 256, 0, stream>>>(x, x_k, MIX);
  gemm_bt<7><<<dim3(64, 16), 256, 0, stream>>>(MIX, WB, k16, nullptr, 2048, 2048, T_);
  cvt1<<<dim3(4096), 256, 0, stream>>>(W_v, WB);
  mix1<<<dim3(16384), 256, 0, stream>>>(x, x_v, MIX);
  gemm_bt<7><<<dim3(64, 16), 256, 0, stream>>>(MIX, WB, v16, nullptr, 2048, 2048, T_);

  prescan2<<<dim3(65536), 256, 0, stream>>>(r16, k16, v16, asig, vsig,
                                            vfst, k_k, k_a, r_k, sb);
  wkv_scan5<<<dim3(256), 256, 0, stream>>>(r16, w32, k16, v16, vsig, asig, y16);
  postk2<<<dim3(65536), 256, 0, stream>>>(y16, v16, sb, g16, lnw, lnb, opre);

  cvt1<<<dim3(4096), 256, 0, stream>>>(W_o, WB);
  gemm_bt<0><<<dim3(64, 16), 256, 0, stream>>>(opre, WB, (float*)d_out, nullptr, 2048, 2048, 0);
}